// Round 5
// baseline (533.655 us; speedup 1.0000x reference)
//
#include <hip/hip_runtime.h>

constexpr int Bn = 8192;   // batch
constexpr int Dn = 512;    // feature dim
#define EPSF 1e-7f
#define MARGINF 1.0f

__device__ __forceinline__ void amax_combine(float& bv, int& bi, float v, int i) {
    // argmax with first-index tie-break (matches jnp.argmax)
    if (v > bv || (v == bv && i < bi)) { bv = v; bi = i; }
}

// ws layout: losses[8192] f32 @0 (32 KB) | bits[256] u32 @32768 (1 KB) | counter u32 @33792
__global__ __launch_bounds__(256) void pack_labels_kernel(const int* __restrict__ labels,
                                                          unsigned* __restrict__ bits) {
    const int tid  = threadIdx.x;
    const int lane = tid & 63;
    const int wv   = tid >> 6;
    __shared__ int s_any;
    if (tid == 0) s_any = 0;
    __syncthreads();
    if (tid < 128 && labels[2 * tid + 1] != 0) atomicOr(&s_any, 1);
    __syncthreads();
    const bool is64 = (s_any == 0);   // int64 labels: odd int32 words all zero
    const long long* l8 = (const long long*)labels;
    for (int r = 0; r < 32; ++r) {
        const int idx = r * 256 + tid;
        unsigned v = is64 ? (unsigned)l8[idx] : (unsigned)labels[idx];
        unsigned long long m = __ballot(v & 1u);
        if (lane == 0) {
            const int w0 = (r * 256 + wv * 64) >> 5;
            bits[w0]     = (unsigned)m;
            bits[w0 + 1] = (unsigned)(m >> 32);
        }
    }
}

__global__ __launch_bounds__(256) void triplet_main(
    const float*    __restrict__ feats,
    const unsigned* __restrict__ bits,
    const float*    __restrict__ noise,
    float*          __restrict__ losses,
    unsigned*       __restrict__ counter,
    float*          __restrict__ out)
{
    __shared__ unsigned sbits[Bn / 32];   // 1 KB label bitmask
    __shared__ float swv[8];
    __shared__ int   swi[8];
    __shared__ float sdist[8];
    __shared__ float sred[4];
    __shared__ int   s_last;

    const int row  = blockIdx.x;
    const int tid  = threadIdx.x;
    const int lane = tid & 63;
    const int wv   = tid >> 6;

    sbits[tid] = bits[tid];               // 1 KB stage, L2-hot
    __syncthreads();

    const unsigned myb = (sbits[row >> 5] >> (row & 31)) & 1u;
    const unsigned xm  = myb ? 0xFu : 0u;
    const int   wb    = tid >> 3;         // word base for this thread's nibble
    const int   shift = (tid & 7) * 4;

    const float* __restrict__ n0 = noise + (size_t)row * Bn;
    const float* __restrict__ n1 = noise + (size_t)Bn * Bn + (size_t)row * Bn;

    // ---- phase A: pos argmax over n0[row][:] (single sequential stream) ----
    float pbv[4] = {-1.0f, -1.0f, -1.0f, -1.0f};
    int   pbi[4] = {0x7FFFFFFF, 0x7FFFFFFF, 0x7FFFFFFF, 0x7FFFFFFF};
#pragma unroll
    for (int it = 0; it < 8; ++it) {
        const int j = tid * 4 + it * 1024;
        float4 v = *(const float4*)(n0 + j);
        // x bit k = (label[j+k] != myLab)
        const unsigned x = ((sbits[wb + it * 32] >> shift) & 0xFu) ^ xm;
        const float* f = (const float*)&v;
#pragma unroll
        for (int k = 0; k < 4; ++k) {
            float c = ((x >> k) & 1u) ? -1.0f : f[k];   // pos: same label
            if (c > pbv[k]) { pbv[k] = c; pbi[k] = j + k; }
        }
    }

    // ---- phase B: neg argmax over n1[row][:] ----
    float nbv[4] = {-1.0f, -1.0f, -1.0f, -1.0f};
    int   nbi[4] = {0x7FFFFFFF, 0x7FFFFFFF, 0x7FFFFFFF, 0x7FFFFFFF};
#pragma unroll
    for (int it = 0; it < 8; ++it) {
        const int j = tid * 4 + it * 1024;
        float4 v = *(const float4*)(n1 + j);
        const unsigned x = ((sbits[wb + it * 32] >> shift) & 0xFu) ^ xm;
        const float* f = (const float*)&v;
#pragma unroll
        for (int k = 0; k < 4; ++k) {
            float c = ((x >> k) & 1u) ? f[k] : -1.0f;   // neg: different label
            if (c > nbv[k]) { nbv[k] = c; nbi[k] = j + k; }
        }
    }

    // merge slots (equal values: lower slot index = lower element index)
    float pv = pbv[0]; int pi_ = pbi[0];
    float nv = nbv[0]; int ni_ = nbi[0];
#pragma unroll
    for (int k = 1; k < 4; ++k) {
        amax_combine(pv, pi_, pbv[k], pbi[k]);
        amax_combine(nv, ni_, nbv[k], nbi[k]);
    }

    // wave-level argmax reduce
    for (int off = 32; off; off >>= 1) {
        float ov = __shfl_down(pv, off, 64);
        int   oi = __shfl_down(pi_, off, 64);
        amax_combine(pv, pi_, ov, oi);
        ov = __shfl_down(nv, off, 64);
        oi = __shfl_down(ni_, off, 64);
        amax_combine(nv, ni_, ov, oi);
    }
    if (lane == 0) { swv[wv] = pv; swi[wv] = pi_; swv[wv + 4] = nv; swi[wv + 4] = ni_; }
    __syncthreads();

    // all threads merge the 4+4 partials (no extra sync stage)
    float bv = swv[0]; int bi = swi[0];
#pragma unroll
    for (int k = 1; k < 4; ++k) amax_combine(bv, bi, swv[k], swi[k]);
    float bv2 = swv[4]; int bi2 = swi[4];
#pragma unroll
    for (int k = 5; k < 8; ++k) amax_combine(bv2, bi2, swv[k], swi[k]);
    const int pi = bi;
    const int ni = (bv2 >= 0.0f) ? bi2 : row;   // has_neg fallback -> anchor

    // ---- triplet distances: each thread 2 contiguous floats ----
    const float2 a  = ((const float2*)(feats + (size_t)row * Dn))[tid];
    const float2 p  = ((const float2*)(feats + (size_t)pi  * Dn))[tid];
    const float2 nn = ((const float2*)(feats + (size_t)ni  * Dn))[tid];

    float dx = a.x - p.x + EPSF, dy = a.y - p.y + EPSF;
    float dap = dx * dx + dy * dy;
    dx = a.x - nn.x + EPSF; dy = a.y - nn.y + EPSF;
    float dan = dx * dx + dy * dy;

    for (int off = 32; off; off >>= 1) {
        dap += __shfl_down(dap, off, 64);
        dan += __shfl_down(dan, off, 64);
    }
    if (lane == 0) { sdist[wv] = dap; sdist[wv + 4] = dan; }
    __syncthreads();

    if (tid == 0) {
        float sap = sdist[0] + sdist[1] + sdist[2] + sdist[3];
        float san = sdist[4] + sdist[5] + sdist[6] + sdist[7];
        float loss = fmaxf(sqrtf(sap) - sqrtf(san) + MARGINF, 0.0f);
        __hip_atomic_store(&losses[row], loss, __ATOMIC_RELAXED, __HIP_MEMORY_SCOPE_AGENT);
        __threadfence();
        unsigned done = atomicAdd(counter, 1u);
        s_last = (done == gridDim.x - 1) ? 1 : 0;
    }
    __syncthreads();

    // ---- last block: deterministic fixed-order mean over all 8192 losses ----
    if (s_last) {
        __threadfence();
        float s = 0.0f;
        for (int k = tid; k < Bn; k += 256)
            s += __hip_atomic_load(&losses[k], __ATOMIC_RELAXED, __HIP_MEMORY_SCOPE_AGENT);
        for (int off = 32; off; off >>= 1) s += __shfl_down(s, off, 64);
        if (lane == 0) sred[wv] = s;
        __syncthreads();
        if (tid == 0) out[0] = (sred[0] + sred[1] + sred[2] + sred[3]) * (1.0f / (float)Bn);
    }
}

extern "C" void kernel_launch(void* const* d_in, const int* in_sizes, int n_in,
                              void* d_out, int out_size, void* d_ws, size_t ws_size,
                              hipStream_t stream) {
    const float* feats  = (const float*)d_in[0];
    const int*   labels = (const int*)d_in[1];
    const float* noise  = (const float*)d_in[2];

    float*    losses  = (float*)d_ws;
    unsigned* bits    = (unsigned*)((char*)d_ws + 32768);
    unsigned* counter = (unsigned*)((char*)d_ws + 33792);

    hipMemsetAsync(counter, 0, 4, stream);   // stream-ordered, graph-capture legal
    pack_labels_kernel<<<1, 256, 0, stream>>>(labels, bits);
    triplet_main<<<Bn, 256, 0, stream>>>(feats, bits, noise, losses, counter, (float*)d_out);
}

// Round 7
// 124.587 us; speedup vs baseline: 4.2834x; 4.2834x over previous
//
#include <hip/hip_runtime.h>

constexpr int Bn = 8192;   // batch
constexpr int Dn = 512;    // feature dim
constexpr int ROWS_PER_BLOCK = 4;
#define EPSF 1e-7f
#define MARGINF 1.0f

__device__ __forceinline__ void amax_combine(float& bv, int& bi, float v, int i) {
    // argmax with first-index tie-break (matches jnp.argmax)
    if (v > bv || (v == bv && i < bi)) { bv = v; bi = i; }
}

// ws layout: int2 idx[8192] @0 (64 KB) | float losses[8192] @65536 (32 KB)
__global__ __launch_bounds__(256) void scan_kernel(
    const int*   __restrict__ labels,
    const float* __restrict__ noise,
    int2*        __restrict__ idx_out)
{
    __shared__ unsigned slab_u[Bn / 4];   // 8 KB label bytes
    __shared__ int s_any;
    __shared__ float swv[ROWS_PER_BLOCK * 8];
    __shared__ int   swi[ROWS_PER_BLOCK * 8];

    const int tid  = threadIdx.x;
    const int lane = tid & 63;
    const int wv   = tid >> 6;

    // ---- label dtype detect (int64 => odd int32 words all zero) ----
    if (tid == 0) s_any = 0;
    __syncthreads();
    if (tid < 128 && labels[2 * tid + 1] != 0) atomicOr(&s_any, 1);
    __syncthreads();
    const bool is64 = (s_any == 0);

    // ---- pack labels into LDS bytes once per block (source L2-hot) ----
    if (is64) {
        const long long* l8 = (const long long*)labels;
        for (int w = tid; w < Bn / 4; w += 256) {
            unsigned b0 = (unsigned)l8[w * 4 + 0] & 0xffu;
            unsigned b1 = (unsigned)l8[w * 4 + 1] & 0xffu;
            unsigned b2 = (unsigned)l8[w * 4 + 2] & 0xffu;
            unsigned b3 = (unsigned)l8[w * 4 + 3] & 0xffu;
            slab_u[w] = b0 | (b1 << 8) | (b2 << 16) | (b3 << 24);
        }
    } else {
        for (int w = tid; w < Bn / 4; w += 256) {
            int4 v = ((const int4*)labels)[w];
            slab_u[w] = ((unsigned)v.x & 0xffu) | (((unsigned)v.y & 0xffu) << 8) |
                        (((unsigned)v.z & 0xffu) << 16) | (((unsigned)v.w & 0xffu) << 24);
        }
    }
    __syncthreads();

    char* slab = (char*)slab_u;

    for (int r = 0; r < ROWS_PER_BLOCK; ++r) {
        const int row = blockIdx.x * ROWS_PER_BLOCK + r;
        const char myLab = slab[row];

        const float* __restrict__ n0 = noise + (size_t)row * Bn;
        const float* __restrict__ n1 = noise + (size_t)Bn * Bn + (size_t)row * Bn;

        // 4 independent slot-accumulators break the dependent compare chain.
        float pbv[4] = {-1.0f, -1.0f, -1.0f, -1.0f};
        float nbv[4] = {-1.0f, -1.0f, -1.0f, -1.0f};
        int   pbi[4] = {0x7FFFFFFF, 0x7FFFFFFF, 0x7FFFFFFF, 0x7FFFFFFF};
        int   nbi[4] = {0x7FFFFFFF, 0x7FFFFFFF, 0x7FFFFFFF, 0x7FFFFFFF};

#pragma unroll 2
        for (int j = tid * 4; j < Bn; j += 256 * 4) {
            float4 v0 = *(const float4*)(n0 + j);
            float4 v1 = *(const float4*)(n1 + j);
            unsigned lw = slab_u[j >> 2];
            const float* f0 = (const float*)&v0;
            const float* f1 = (const float*)&v1;
#pragma unroll
            for (int k = 0; k < 4; ++k) {
                char lk = (char)((lw >> (k * 8)) & 0xffu);
                // within a slot indices strictly increase -> strictly-greater keeps first max
                float cp = (lk == myLab) ? f0[k] : -1.0f;
                if (cp > pbv[k]) { pbv[k] = cp; pbi[k] = j + k; }
                float cn = (lk != myLab) ? f1[k] : -1.0f;
                if (cn > nbv[k]) { nbv[k] = cn; nbi[k] = j + k; }
            }
        }

        // merge slots (equal values: lower slot = lower index)
        float pv = pbv[0]; int pi_ = pbi[0];
        float nv = nbv[0]; int ni_ = nbi[0];
#pragma unroll
        for (int k = 1; k < 4; ++k) {
            amax_combine(pv, pi_, pbv[k], pbi[k]);
            amax_combine(nv, ni_, nbv[k], nbi[k]);
        }

        // wave-level argmax reduce
        for (int off = 32; off; off >>= 1) {
            float ov = __shfl_down(pv, off, 64);
            int   oi = __shfl_down(pi_, off, 64);
            amax_combine(pv, pi_, ov, oi);
            ov = __shfl_down(nv, off, 64);
            oi = __shfl_down(ni_, off, 64);
            amax_combine(nv, ni_, ov, oi);
        }
        // per-row LDS slots -> only one barrier per row (no WAR on next row)
        const int r8 = r * 8;
        if (lane == 0) { swv[r8 + wv] = pv; swi[r8 + wv] = pi_;
                         swv[r8 + 4 + wv] = nv; swi[r8 + 4 + wv] = ni_; }
        __syncthreads();

        if (tid == 0) {
            float bv = swv[r8]; int bi = swi[r8];
#pragma unroll
            for (int k = 1; k < 4; ++k) amax_combine(bv, bi, swv[r8 + k], swi[r8 + k]);
            float bv2 = swv[r8 + 4]; int bi2 = swi[r8 + 4];
#pragma unroll
            for (int k = 5; k < 8; ++k) amax_combine(bv2, bi2, swv[r8 + k], swi[r8 + k]);
            idx_out[row] = make_int2(bi, (bv2 >= 0.0f) ? bi2 : row);  // has_neg fallback
        }
        // no second barrier: next row uses different LDS slots
    }
}

// wave-per-row triplet distance; feats (16 MB) is L3-resident
__global__ __launch_bounds__(256) void dist_kernel(
    const float* __restrict__ feats,
    const int2*  __restrict__ idx,
    float*       __restrict__ losses)
{
    const int tid  = threadIdx.x;
    const int lane = tid & 63;
    const int wv   = tid >> 6;
    const int row  = blockIdx.x * 4 + wv;

    const int2 pn = idx[row];
    const float* fa = feats + (size_t)row  * Dn;
    const float* fp = feats + (size_t)pn.x * Dn;
    const float* fn = feats + (size_t)pn.y * Dn;

    float dap = 0.0f, dan = 0.0f;
#pragma unroll
    for (int c = 0; c < 2; ++c) {
        const int o = c * 256 + lane * 4;
        float4 a = *(const float4*)(fa + o);
        float4 p = *(const float4*)(fp + o);
        float4 q = *(const float4*)(fn + o);
        float d;
        d = a.x - p.x + EPSF; dap += d * d;
        d = a.y - p.y + EPSF; dap += d * d;
        d = a.z - p.z + EPSF; dap += d * d;
        d = a.w - p.w + EPSF; dap += d * d;
        d = a.x - q.x + EPSF; dan += d * d;
        d = a.y - q.y + EPSF; dan += d * d;
        d = a.z - q.z + EPSF; dan += d * d;
        d = a.w - q.w + EPSF; dan += d * d;
    }
    for (int off = 32; off; off >>= 1) {
        dap += __shfl_down(dap, off, 64);
        dan += __shfl_down(dan, off, 64);
    }
    if (lane == 0)
        losses[row] = fmaxf(sqrtf(dap) - sqrtf(dan) + MARGINF, 0.0f);
}

// deterministic mean over Bn losses, single block
__global__ __launch_bounds__(256) void reduce_mean_kernel(
    const float* __restrict__ losses, float* __restrict__ out)
{
    const int tid  = threadIdx.x;
    const int lane = tid & 63;
    const int wv   = tid >> 6;
    float s = 0.0f;
    for (int k = tid; k < Bn; k += 256) s += losses[k];
    for (int off = 32; off; off >>= 1) s += __shfl_down(s, off, 64);
    __shared__ float sw[4];
    if (lane == 0) sw[wv] = s;
    __syncthreads();
    if (tid == 0) out[0] = (sw[0] + sw[1] + sw[2] + sw[3]) * (1.0f / (float)Bn);
}

extern "C" void kernel_launch(void* const* d_in, const int* in_sizes, int n_in,
                              void* d_out, int out_size, void* d_ws, size_t ws_size,
                              hipStream_t stream) {
    const float* feats  = (const float*)d_in[0];
    const int*   labels = (const int*)d_in[1];
    const float* noise  = (const float*)d_in[2];

    int2*  idx    = (int2*)d_ws;                       // 64 KB
    float* losses = (float*)((char*)d_ws + 65536);     // 32 KB

    scan_kernel<<<Bn / ROWS_PER_BLOCK, 256, 0, stream>>>(labels, noise, idx);
    dist_kernel<<<Bn / 4, 256, 0, stream>>>(feats, idx, losses);
    reduce_mean_kernel<<<1, 256, 0, stream>>>(losses, (float*)d_out);
}

// Round 8
// 122.500 us; speedup vs baseline: 4.3564x; 1.0170x over previous
//
#include <hip/hip_runtime.h>

constexpr int Bn = 8192;   // batch
constexpr int Dn = 512;    // feature dim
#define EPSF 1e-7f
#define MARGINF 1.0f

__device__ __forceinline__ void amax_combine(float& bv, int& bi, float v, int i) {
    // argmax with first-index tie-break (matches jnp.argmax)
    if (v > bv || (v == bv && i < bi)) { bv = v; bi = i; }
}

// ws layout: pos_idx[8192] i32 @0 | neg_idx[8192] i32 @32768 | losses[8192] f32 @65536 | bits[256] u32 @98304
__global__ __launch_bounds__(256) void pack_labels_kernel(const int* __restrict__ labels,
                                                          unsigned* __restrict__ bits) {
    const int tid  = threadIdx.x;
    const int lane = tid & 63;
    const int wv   = tid >> 6;
    __shared__ int s_any;
    if (tid == 0) s_any = 0;
    __syncthreads();
    if (tid < 128 && labels[2 * tid + 1] != 0) atomicOr(&s_any, 1);
    __syncthreads();
    const bool is64 = (s_any == 0);   // int64 labels: odd int32 words all zero
    const long long* l8 = (const long long*)labels;
    for (int r = 0; r < 32; ++r) {
        const int idx = r * 256 + tid;
        unsigned v = is64 ? (unsigned)l8[idx] : (unsigned)labels[idx];
        unsigned long long m = __ballot(v & 1u);
        if (lane == 0) {
            const int w0 = (r * 256 + wv * 64) >> 5;
            bits[w0]     = (unsigned)m;
            bits[w0 + 1] = (unsigned)(m >> 32);
        }
    }
}

// One block scans ONE 32KB noise row, one polarity. blockIdx < Bn: pos over
// noise[0]; else neg over noise[1]. Single sequential stream, 8 float4 loads
// in flight per thread.
__global__ __launch_bounds__(256) void scan_kernel(
    const unsigned* __restrict__ bits,
    const float*    __restrict__ noise,
    int*            __restrict__ pos_idx,
    int*            __restrict__ neg_idx)
{
    __shared__ unsigned sbits[Bn / 32];   // 1 KB label bitmask
    __shared__ float swv[4];
    __shared__ int   swi[4];

    const int tid  = threadIdx.x;
    const int lane = tid & 63;
    const int wv   = tid >> 6;

    sbits[tid] = bits[tid];
    __syncthreads();

    const bool neg = (blockIdx.x >= Bn);
    const int  row = neg ? (blockIdx.x - Bn) : blockIdx.x;

    const unsigned myb = (sbits[row >> 5] >> (row & 31)) & 1u;
    const unsigned xm  = myb ? 0xFFFFFFFFu : 0u;

    const float* __restrict__ src = noise + (neg ? (size_t)Bn * Bn : (size_t)0)
                                          + (size_t)row * Bn;

    // 8 independent slot-accumulators (one per float in the 32B packet)
    float bv[8] = {-1,-1,-1,-1,-1,-1,-1,-1};
    int   bi[8] = {0x7FFFFFFF,0x7FFFFFFF,0x7FFFFFFF,0x7FFFFFFF,
                   0x7FFFFFFF,0x7FFFFFFF,0x7FFFFFFF,0x7FFFFFFF};

#pragma unroll
    for (int it = 0; it < 4; ++it) {
        const int j = tid * 8 + it * 2048;
        float4 va = *(const float4*)(src + j);
        float4 vb = *(const float4*)(src + j + 4);
        // u bit k==1 -> element j+k participates in this polarity's argmax
        unsigned u = (sbits[(tid >> 2) + it * 64] >> ((tid & 3) * 8)) ^ xm;
        if (!neg) u = ~u;
        const float f[8] = {va.x, va.y, va.z, va.w, vb.x, vb.y, vb.z, vb.w};
#pragma unroll
        for (int k = 0; k < 8; ++k) {
            float c = ((u >> k) & 1u) ? f[k] : -1.0f;
            // within a slot indices strictly increase -> '>' keeps first max
            if (c > bv[k]) { bv[k] = c; bi[k] = j + k; }
        }
    }

    // merge slots (equal values: lower slot = lower index)
    float v = bv[0]; int i = bi[0];
#pragma unroll
    for (int k = 1; k < 8; ++k) amax_combine(v, i, bv[k], bi[k]);

    // wave reduce
    for (int off = 32; off; off >>= 1) {
        float ov = __shfl_down(v, off, 64);
        int   oi = __shfl_down(i, off, 64);
        amax_combine(v, i, ov, oi);
    }
    if (lane == 0) { swv[wv] = v; swi[wv] = i; }
    __syncthreads();

    if (tid == 0) {
        float fv = swv[0]; int fi = swi[0];
#pragma unroll
        for (int k = 1; k < 4; ++k) amax_combine(fv, fi, swv[k], swi[k]);
        if (neg) neg_idx[row] = (fv >= 0.0f) ? fi : row;  // has_neg fallback -> anchor
        else     pos_idx[row] = fi;
    }
}

// wave-per-row triplet distance; feats (16 MB) is L3-resident
__global__ __launch_bounds__(256) void dist_kernel(
    const float* __restrict__ feats,
    const int*   __restrict__ pos_idx,
    const int*   __restrict__ neg_idx,
    float*       __restrict__ losses)
{
    const int tid  = threadIdx.x;
    const int lane = tid & 63;
    const int wv   = tid >> 6;
    const int row  = blockIdx.x * 4 + wv;

    const int pi = pos_idx[row];
    const int ni = neg_idx[row];
    const float* fa = feats + (size_t)row * Dn;
    const float* fp = feats + (size_t)pi  * Dn;
    const float* fn = feats + (size_t)ni  * Dn;

    float dap = 0.0f, dan = 0.0f;
#pragma unroll
    for (int c = 0; c < 2; ++c) {
        const int o = c * 256 + lane * 4;
        float4 a = *(const float4*)(fa + o);
        float4 p = *(const float4*)(fp + o);
        float4 q = *(const float4*)(fn + o);
        float d;
        d = a.x - p.x + EPSF; dap += d * d;
        d = a.y - p.y + EPSF; dap += d * d;
        d = a.z - p.z + EPSF; dap += d * d;
        d = a.w - p.w + EPSF; dap += d * d;
        d = a.x - q.x + EPSF; dan += d * d;
        d = a.y - q.y + EPSF; dan += d * d;
        d = a.z - q.z + EPSF; dan += d * d;
        d = a.w - q.w + EPSF; dan += d * d;
    }
    for (int off = 32; off; off >>= 1) {
        dap += __shfl_down(dap, off, 64);
        dan += __shfl_down(dan, off, 64);
    }
    if (lane == 0)
        losses[row] = fmaxf(sqrtf(dap) - sqrtf(dan) + MARGINF, 0.0f);
}

// deterministic mean over Bn losses, single block
__global__ __launch_bounds__(256) void reduce_mean_kernel(
    const float* __restrict__ losses, float* __restrict__ out)
{
    const int tid  = threadIdx.x;
    const int lane = tid & 63;
    const int wv   = tid >> 6;
    float s = 0.0f;
    for (int k = tid; k < Bn; k += 256) s += losses[k];
    for (int off = 32; off; off >>= 1) s += __shfl_down(s, off, 64);
    __shared__ float sw[4];
    if (lane == 0) sw[wv] = s;
    __syncthreads();
    if (tid == 0) out[0] = (sw[0] + sw[1] + sw[2] + sw[3]) * (1.0f / (float)Bn);
}

extern "C" void kernel_launch(void* const* d_in, const int* in_sizes, int n_in,
                              void* d_out, int out_size, void* d_ws, size_t ws_size,
                              hipStream_t stream) {
    const float* feats  = (const float*)d_in[0];
    const int*   labels = (const int*)d_in[1];
    const float* noise  = (const float*)d_in[2];

    int*      pos_idx = (int*)d_ws;
    int*      neg_idx = (int*)((char*)d_ws + 32768);
    float*    losses  = (float*)((char*)d_ws + 65536);
    unsigned* bits    = (unsigned*)((char*)d_ws + 98304);

    pack_labels_kernel<<<1, 256, 0, stream>>>(labels, bits);
    scan_kernel<<<2 * Bn, 256, 0, stream>>>(bits, noise, pos_idx, neg_idx);
    dist_kernel<<<Bn / 4, 256, 0, stream>>>(feats, pos_idx, neg_idx, losses);
    reduce_mean_kernel<<<1, 256, 0, stream>>>(losses, (float*)d_out);
}

// Round 9
// 117.432 us; speedup vs baseline: 4.5444x; 1.0432x over previous
//
#include <hip/hip_runtime.h>

constexpr int Bn = 8192;   // batch
constexpr int Dn = 512;    // feature dim
#define EPSF 1e-7f
#define MARGINF 1.0f

using f32x4 = __attribute__((ext_vector_type(4))) float;

__device__ __forceinline__ f32x4 ntload4(const float* p) {
    return __builtin_nontemporal_load((const f32x4*)p);   // 16B nt load, bypasses L2/L3 alloc
}

__device__ __forceinline__ void amax_combine(float& bv, int& bi, float v, int i) {
    // argmax with first-index tie-break (matches jnp.argmax)
    if (v > bv || (v == bv && i < bi)) { bv = v; bi = i; }
}

// ws layout: losses[8192] f32 @0 (32 KB) | bits[256] u32 @32768 (1 KB)
__global__ __launch_bounds__(256) void pack_labels_kernel(const int* __restrict__ labels,
                                                          unsigned* __restrict__ bits) {
    const int tid  = threadIdx.x;
    const int lane = tid & 63;
    const int wv   = tid >> 6;
    __shared__ int s_any;
    if (tid == 0) s_any = 0;
    __syncthreads();
    if (tid < 128 && labels[2 * tid + 1] != 0) atomicOr(&s_any, 1);
    __syncthreads();
    const bool is64 = (s_any == 0);   // int64 labels: odd int32 words all zero
    const long long* l8 = (const long long*)labels;
    for (int r = 0; r < 32; ++r) {
        const int idx = r * 256 + tid;
        unsigned v = is64 ? (unsigned)l8[idx] : (unsigned)labels[idx];
        unsigned long long m = __ballot(v & 1u);
        if (lane == 0) {
            const int w0 = (r * 256 + wv * 64) >> 5;
            bits[w0]     = (unsigned)m;
            bits[w0 + 1] = (unsigned)(m >> 32);
        }
    }
}

// Block-per-row fused scan (pos+neg argmax over the two noise rows) + triplet
// distance. Noise read via non-temporal loads (stream, zero reuse).
__global__ __launch_bounds__(256) void fused_kernel(
    const float*    __restrict__ feats,
    const unsigned* __restrict__ bits,
    const float*    __restrict__ noise,
    float*          __restrict__ losses)
{
    __shared__ unsigned sbits[Bn / 32];   // 1 KB label bitmask
    __shared__ float swv[8];
    __shared__ int   swi[8];
    __shared__ float sdist[8];

    const int row  = blockIdx.x;
    const int tid  = threadIdx.x;
    const int lane = tid & 63;
    const int wv   = tid >> 6;

    sbits[tid] = bits[tid];
    __syncthreads();

    const unsigned myb  = (sbits[row >> 5] >> (row & 31)) & 1u;
    const unsigned flip = myb ? 0u : 0xFFu;   // pb bit k = (label[j+k] == myLab)

    const float* __restrict__ n0 = noise + (size_t)row * Bn;
    const float* __restrict__ n1 = noise + (size_t)Bn * Bn + (size_t)row * Bn;

    // 8 independent slot-accumulators per polarity (break the compare chain)
    float pbv[8], nbv[8]; int pbi[8], nbi[8];
#pragma unroll
    for (int k = 0; k < 8; ++k) { pbv[k] = nbv[k] = -1.0f; pbi[k] = nbi[k] = 0x7FFFFFFF; }

    const int shift = (tid & 3) * 8;
#pragma unroll 2
    for (int it = 0; it < 4; ++it) {
        const int j = tid * 8 + it * 2048;
        f32x4 a0 = ntload4(n0 + j);
        f32x4 a1 = ntload4(n0 + j + 4);
        f32x4 b0 = ntload4(n1 + j);
        f32x4 b1 = ntload4(n1 + j + 4);
        const unsigned pb = ((sbits[(tid >> 2) + it * 64] >> shift) & 0xFFu) ^ flip;
        const float fa[8] = {a0.x, a0.y, a0.z, a0.w, a1.x, a1.y, a1.z, a1.w};
        const float fb[8] = {b0.x, b0.y, b0.z, b0.w, b1.x, b1.y, b1.z, b1.w};
#pragma unroll
        for (int k = 0; k < 8; ++k) {
            // within a slot indices strictly increase -> '>' keeps first max
            float cp = ((pb >> k) & 1u) ? fa[k] : -1.0f;
            if (cp > pbv[k]) { pbv[k] = cp; pbi[k] = j + k; }
            float cn = ((pb >> k) & 1u) ? -1.0f : fb[k];
            if (cn > nbv[k]) { nbv[k] = cn; nbi[k] = j + k; }
        }
    }

    // merge slots (equal values: lower slot = lower index)
    float pv = pbv[0]; int pi_ = pbi[0];
    float nv = nbv[0]; int ni_ = nbi[0];
#pragma unroll
    for (int k = 1; k < 8; ++k) {
        amax_combine(pv, pi_, pbv[k], pbi[k]);
        amax_combine(nv, ni_, nbv[k], nbi[k]);
    }

    // wave-level argmax reduce
    for (int off = 32; off; off >>= 1) {
        float ov = __shfl_down(pv, off, 64);
        int   oi = __shfl_down(pi_, off, 64);
        amax_combine(pv, pi_, ov, oi);
        ov = __shfl_down(nv, off, 64);
        oi = __shfl_down(ni_, off, 64);
        amax_combine(nv, ni_, ov, oi);
    }
    if (lane == 0) { swv[wv] = pv; swi[wv] = pi_; swv[wv + 4] = nv; swi[wv + 4] = ni_; }
    __syncthreads();

    // all threads merge the 4+4 wave partials (result uniform across block)
    float bv = swv[0]; int bi = swi[0];
#pragma unroll
    for (int k = 1; k < 4; ++k) amax_combine(bv, bi, swv[k], swi[k]);
    float bv2 = swv[4]; int bi2 = swi[4];
#pragma unroll
    for (int k = 5; k < 8; ++k) amax_combine(bv2, bi2, swv[k], swi[k]);
    const int pi = bi;
    const int ni = (bv2 >= 0.0f) ? bi2 : row;   // has_neg fallback -> anchor

    // ---- triplet distances: each thread 2 contiguous floats (feats L3-resident) ----
    const float2 a  = ((const float2*)(feats + (size_t)row * Dn))[tid];
    const float2 p  = ((const float2*)(feats + (size_t)pi  * Dn))[tid];
    const float2 nn = ((const float2*)(feats + (size_t)ni  * Dn))[tid];

    float dx = a.x - p.x + EPSF, dy = a.y - p.y + EPSF;
    float dap = dx * dx + dy * dy;
    dx = a.x - nn.x + EPSF; dy = a.y - nn.y + EPSF;
    float dan = dx * dx + dy * dy;

    for (int off = 32; off; off >>= 1) {
        dap += __shfl_down(dap, off, 64);
        dan += __shfl_down(dan, off, 64);
    }
    if (lane == 0) { sdist[wv] = dap; sdist[wv + 4] = dan; }
    __syncthreads();

    if (tid == 0) {
        float sap = sdist[0] + sdist[1] + sdist[2] + sdist[3];
        float san = sdist[4] + sdist[5] + sdist[6] + sdist[7];
        losses[row] = fmaxf(sqrtf(sap) - sqrtf(san) + MARGINF, 0.0f);
    }
}

// deterministic mean over Bn losses, single block
__global__ __launch_bounds__(256) void reduce_mean_kernel(
    const float* __restrict__ losses, float* __restrict__ out)
{
    const int tid  = threadIdx.x;
    const int lane = tid & 63;
    const int wv   = tid >> 6;
    float s = 0.0f;
    for (int k = tid; k < Bn; k += 256) s += losses[k];
    for (int off = 32; off; off >>= 1) s += __shfl_down(s, off, 64);
    __shared__ float sw[4];
    if (lane == 0) sw[wv] = s;
    __syncthreads();
    if (tid == 0) out[0] = (sw[0] + sw[1] + sw[2] + sw[3]) * (1.0f / (float)Bn);
}

extern "C" void kernel_launch(void* const* d_in, const int* in_sizes, int n_in,
                              void* d_out, int out_size, void* d_ws, size_t ws_size,
                              hipStream_t stream) {
    const float* feats  = (const float*)d_in[0];
    const int*   labels = (const int*)d_in[1];
    const float* noise  = (const float*)d_in[2];

    float*    losses = (float*)d_ws;                       // 32 KB
    unsigned* bits   = (unsigned*)((char*)d_ws + 32768);   // 1 KB

    pack_labels_kernel<<<1, 256, 0, stream>>>(labels, bits);
    fused_kernel<<<Bn, 256, 0, stream>>>(feats, bits, noise, losses);
    reduce_mean_kernel<<<1, 256, 0, stream>>>(losses, (float*)d_out);
}

// Round 10
// 103.161 us; speedup vs baseline: 5.1730x; 1.1383x over previous
//
#include <hip/hip_runtime.h>

constexpr int Bn = 8192;   // batch
constexpr int Dn = 512;    // feature dim
#define EPSF 1e-7f
#define MARGINF 1.0f

using f32x4 = __attribute__((ext_vector_type(4))) float;

__device__ __forceinline__ f32x4 ntload4(const float* p) {
    return __builtin_nontemporal_load((const f32x4*)p);   // streaming load, no cache alloc
}

__device__ __forceinline__ void amax_combine(float& bv, int& bi, float v, int i) {
    // argmax with first-index tie-break (matches jnp.argmax)
    if (v > bv || (v == bv && i < bi)) { bv = v; bi = i; }
}

// ws layout: losses[8192] f32 @0 (32 KB) | packed[2048] u32 @32768 (8 KB)
__global__ __launch_bounds__(256) void pack_labels_kernel(const int* __restrict__ labels,
                                                          unsigned* __restrict__ packed) {
    __shared__ int s_any;
    const int tid = threadIdx.x;
    if (tid == 0) s_any = 0;
    __syncthreads();
    if (tid < 128 && labels[2 * tid + 1] != 0) atomicOr(&s_any, 1);
    __syncthreads();
    const bool is64 = (s_any == 0);   // int64 labels: odd int32 words all zero

    if (is64) {
        const long long* l8 = (const long long*)labels;
        for (int w = tid; w < Bn / 4; w += 256) {
            unsigned b0 = (unsigned)l8[w * 4 + 0] & 0xffu;
            unsigned b1 = (unsigned)l8[w * 4 + 1] & 0xffu;
            unsigned b2 = (unsigned)l8[w * 4 + 2] & 0xffu;
            unsigned b3 = (unsigned)l8[w * 4 + 3] & 0xffu;
            packed[w] = b0 | (b1 << 8) | (b2 << 16) | (b3 << 24);
        }
    } else {
        for (int w = tid; w < Bn / 4; w += 256) {
            int4 v = ((const int4*)labels)[w];
            packed[w] = ((unsigned)v.x & 0xffu) | (((unsigned)v.y & 0xffu) << 8) |
                        (((unsigned)v.z & 0xffu) << 16) | (((unsigned)v.w & 0xffu) << 24);
        }
    }
}

// Block-per-row fused scan (pos+neg argmax) + triplet distance.
// Dense per-wave addressing (lane i at 16B*i), fully unrolled -> 16 nt loads in flight.
__global__ __launch_bounds__(256) void triplet_main(
    const float*    __restrict__ feats,
    const unsigned* __restrict__ packed,
    const float*    __restrict__ noise,
    float*          __restrict__ losses)
{
    __shared__ unsigned slab_u[Bn / 4];   // 8 KB packed label bytes
    __shared__ float swv[8];
    __shared__ int   swi[8];
    __shared__ float sdist[8];

    const int row  = blockIdx.x;
    const int tid  = threadIdx.x;
    const int lane = tid & 63;
    const int wv   = tid >> 6;

    // stage packed labels into LDS (source is L2-hot, 8 KB)
    for (int k = tid; k < Bn / 16; k += 256)
        ((uint4*)slab_u)[k] = ((const uint4*)packed)[k];
    __syncthreads();

    const unsigned myLab = (slab_u[row >> 2] >> ((row & 3) * 8)) & 0xffu;

    const float* __restrict__ n0 = noise + (size_t)row * Bn;
    const float* __restrict__ n1 = noise + (size_t)Bn * Bn + (size_t)row * Bn;

    // 4 independent slot-accumulators break the dependent compare chain.
    float pbv[4] = {-1.0f, -1.0f, -1.0f, -1.0f};
    float nbv[4] = {-1.0f, -1.0f, -1.0f, -1.0f};
    int   pbi[4] = {0x7FFFFFFF, 0x7FFFFFFF, 0x7FFFFFFF, 0x7FFFFFFF};
    int   nbi[4] = {0x7FFFFFFF, 0x7FFFFFFF, 0x7FFFFFFF, 0x7FFFFFFF};

#pragma unroll
    for (int it = 0; it < 8; ++it) {
        const int j = tid * 4 + it * 1024;
        f32x4 v0 = ntload4(n0 + j);
        f32x4 v1 = ntload4(n1 + j);
        unsigned lw = slab_u[j >> 2];
        const float f0[4] = {v0.x, v0.y, v0.z, v0.w};
        const float f1[4] = {v1.x, v1.y, v1.z, v1.w};
#pragma unroll
        for (int k = 0; k < 4; ++k) {
            unsigned lk = (lw >> (k * 8)) & 0xffu;
            // within a slot indices strictly increase -> '>' keeps first max
            float cp = (lk == myLab) ? f0[k] : -1.0f;
            if (cp > pbv[k]) { pbv[k] = cp; pbi[k] = j + k; }
            float cn = (lk != myLab) ? f1[k] : -1.0f;
            if (cn > nbv[k]) { nbv[k] = cn; nbi[k] = j + k; }
        }
    }

    // merge slots (equal values: lower slot = lower index)
    float pv = pbv[0]; int pi_ = pbi[0];
    float nv = nbv[0]; int ni_ = nbi[0];
#pragma unroll
    for (int k = 1; k < 4; ++k) {
        amax_combine(pv, pi_, pbv[k], pbi[k]);
        amax_combine(nv, ni_, nbv[k], nbi[k]);
    }

    // wave-level argmax reduce
    for (int off = 32; off; off >>= 1) {
        float ov = __shfl_down(pv, off, 64);
        int   oi = __shfl_down(pi_, off, 64);
        amax_combine(pv, pi_, ov, oi);
        ov = __shfl_down(nv, off, 64);
        oi = __shfl_down(ni_, off, 64);
        amax_combine(nv, ni_, ov, oi);
    }
    if (lane == 0) { swv[wv] = pv; swi[wv] = pi_; swv[wv + 4] = nv; swi[wv + 4] = ni_; }
    __syncthreads();

    // all threads merge the 4+4 wave partials (uniform result)
    float bv = swv[0]; int bi = swi[0];
#pragma unroll
    for (int k = 1; k < 4; ++k) amax_combine(bv, bi, swv[k], swi[k]);
    float bv2 = swv[4]; int bi2 = swi[4];
#pragma unroll
    for (int k = 5; k < 8; ++k) amax_combine(bv2, bi2, swv[k], swi[k]);
    const int pi = bi;
    const int ni = (bv2 >= 0.0f) ? bi2 : row;   // has_neg fallback -> anchor

    // ---- triplet distances: each thread 2 contiguous floats (feats cached) ----
    const float2 a  = ((const float2*)(feats + (size_t)row * Dn))[tid];
    const float2 p  = ((const float2*)(feats + (size_t)pi  * Dn))[tid];
    const float2 nn = ((const float2*)(feats + (size_t)ni  * Dn))[tid];

    float dx = a.x - p.x + EPSF, dy = a.y - p.y + EPSF;
    float dap = dx * dx + dy * dy;
    dx = a.x - nn.x + EPSF; dy = a.y - nn.y + EPSF;
    float dan = dx * dx + dy * dy;

    for (int off = 32; off; off >>= 1) {
        dap += __shfl_down(dap, off, 64);
        dan += __shfl_down(dan, off, 64);
    }
    if (lane == 0) { sdist[wv] = dap; sdist[wv + 4] = dan; }
    __syncthreads();

    if (tid == 0) {
        float sap = sdist[0] + sdist[1] + sdist[2] + sdist[3];
        float san = sdist[4] + sdist[5] + sdist[6] + sdist[7];
        losses[row] = fmaxf(sqrtf(sap) - sqrtf(san) + MARGINF, 0.0f);
    }
}

// deterministic mean over Bn losses, single block
__global__ __launch_bounds__(256) void reduce_mean_kernel(
    const float* __restrict__ losses, float* __restrict__ out)
{
    const int tid  = threadIdx.x;
    const int lane = tid & 63;
    const int wv   = tid >> 6;
    float s = 0.0f;
    for (int k = tid; k < Bn; k += 256) s += losses[k];
    for (int off = 32; off; off >>= 1) s += __shfl_down(s, off, 64);
    __shared__ float sw[4];
    if (lane == 0) sw[wv] = s;
    __syncthreads();
    if (tid == 0) out[0] = (sw[0] + sw[1] + sw[2] + sw[3]) * (1.0f / (float)Bn);
}

extern "C" void kernel_launch(void* const* d_in, const int* in_sizes, int n_in,
                              void* d_out, int out_size, void* d_ws, size_t ws_size,
                              hipStream_t stream) {
    const float* feats  = (const float*)d_in[0];
    const int*   labels = (const int*)d_in[1];
    const float* noise  = (const float*)d_in[2];

    float*    losses = (float*)d_ws;                       // 32 KB
    unsigned* packed = (unsigned*)((char*)d_ws + 32768);   // 8 KB

    pack_labels_kernel<<<1, 256, 0, stream>>>(labels, packed);
    triplet_main<<<Bn, 256, 0, stream>>>(feats, packed, noise, losses);
    reduce_mean_kernel<<<1, 256, 0, stream>>>(losses, (float*)d_out);
}